// Round 19
// baseline (129.006 us; speedup 1.0000x reference)
//
#include <hip/hip_runtime.h>

// ---------------------------------------------------------------------------
// KernelClassifier: px = x@Wp+bp; pX = X@Wp+bp; Kis = exp(-||px-pX||^2/256)
// (drop self: Kis<1.0f), pred[b,lab[i]] += Kis[b,i], normalize, rank-gather.
// R4: LDS fp32 atomicAdd = CAS loop -> fixed-point ds_add_u32 (451->216us).
// R11-R13: counted-vmcnt pipelines, bank fix, kernel merges (216->112us).
// R14-R17: null/negative levers; R18 = R15 optimum + label consolidation
//     (110.6us).
// R19: k_main dynamic tile-stealing (391 % 96 = 7 columns did +25% work ->
//     makespan tail). Deterministic because partials revert to u32
//     fixed-point (integer bin sums are partition-independent; bf16 partials
//     would not be). Per-bt counters zeroed by k_pack_wp each launch;
//     next-grab prefetched under current tile's compute.
// ---------------------------------------------------------------------------

typedef short  bf8v  __attribute__((ext_vector_type(8)));   // 8 x bf16 (4 VGPR)
typedef float  f32x4 __attribute__((ext_vector_type(4)));   // MFMA C/D

#define NTRAIN 50000
#define NPAD   50048          // 391 * 128
#define NTILES 391
#define BQ     1024
#define DIN    768
#define DP     128
#define NCLS   100
#define PSTRIDE 102           // LDS bins stride: 102%32=6 -> g-lanes spread
#define PCOLS  104            // partial row width (u32-pair aligned)
#define FIXS   2097152.0f     // 2^21 fixed-point scale
#define FIXI   (1.0f / 2097152.0f)
#define NBX    (NPAD / 64)    // 782 projX blocks
#define NBQ    (BQ / 64)      // 16 projx blocks
#define NBL    ((NPAD + 15) / 16)   // label blocks: 4 waves x 4 rows each

__device__ __forceinline__ short f2bf(float x) {   // fp32 -> bf16 RNE
    unsigned u = __float_as_uint(x);
    u += 0x7FFFu + ((u >> 16) & 1u);
    return (short)(u >> 16);
}

#define AS1U(p) ((const __attribute__((address_space(1))) unsigned int*)(unsigned long long)(p))
#define AS3U(p) ((__attribute__((address_space(3))) unsigned int*)(unsigned int)(unsigned long long)(p))

// ---------------------------------------------------------------------------
// Kernel 0: pack Wp into B-fragment order; also zero the 8 steal counters.
// ---------------------------------------------------------------------------
__global__ __launch_bounds__(256) void k_pack_wp(const float* __restrict__ Wp,
                                                 short* __restrict__ WpP,
                                                 unsigned* __restrict__ cnt) {
    if (blockIdx.x == 0 && threadIdx.x < 8) cnt[threadIdx.x] = 0u;
    int tid = blockIdx.x * 256 + threadIdx.x;
    if (tid >= 24 * 8 * 64) return;
    int l = tid & 63, cb = (tid >> 6) & 7, q = tid >> 9;
    int c = cb * 16 + (l & 15);
    int g = l >> 4;
    bf8v o;
#pragma unroll
    for (int j = 0; j < 8; ++j) {
        int k = q * 32 + g * 8 + j;
        o[j] = f2bf(Wp[k * DP + c]);
    }
    *reinterpret_cast<bf8v*>(WpP + (size_t)tid * 8) = o;
}

// ---------------------------------------------------------------------------
// proj body (R13/R15 pipeline): BM=64, 4 waves x 16 rows, barrier-free,
// counted vmcnt, depth-2 A staging, single-buffer B regs.
// ---------------------------------------------------------------------------
__device__ __forceinline__ void proj_body(const float* __restrict__ Xin,
                                          const short* __restrict__ WpP,
                                          const float* __restrict__ bp,
                                          short* __restrict__ outP,
                                          float* __restrict__ normv,
                                          int Mreal, int blk,
                                          float* __restrict__ Xlds) {
    const int tid = threadIdx.x;
    const int w = tid >> 6, l = tid & 63, g = l >> 4, li = l & 15;
    const int rowblk = blk * 64;

    f32x4 acc[8];
#pragma unroll
    for (int cb = 0; cb < 8; ++cb) acc[cb] = (f32x4){0.f, 0.f, 0.f, 0.f};

#define STAGE64(lbuf, kb)                                                     \
    {                                                                         \
        _Pragma("unroll")                                                     \
        for (int it = 0; it < 4; ++it) {                                      \
            int s  = w * 256 + it * 64 + l;                                   \
            int r  = s >> 4;                                                  \
            int c4 = (s & 15) ^ (r & 7);                                      \
            int rg = rowblk + r;                                              \
            rg = (rg < Mreal) ? rg : (Mreal - 1);                             \
            const float* gp = Xin + (size_t)rg * DIN + (kb) * 64 + c4 * 4;    \
            const float* lp = (lbuf) + (w * 256 + it * 64) * 4;               \
            __builtin_amdgcn_global_load_lds(AS1U(gp), AS3U(lp), 16, 0, 0);   \
        }                                                                     \
    }
#define ISSUE_B(dst, kb)                                                      \
    {                                                                         \
        _Pragma("unroll")                                                     \
        for (int f = 0; f < 16; ++f)                                          \
            dst[f] = *reinterpret_cast<const bf8v*>(                          \
                WpP + ((size_t)((kb) * 16 + f) * 64 + l) * 8);                \
    }

    bf8v breg[16];
    float4 a[4];

    STAGE64(Xlds, 0);
    STAGE64(Xlds + 4096, 1);
    ISSUE_B(breg, 0);

#pragma unroll 1
    for (int kb = 0; kb < 12; ++kb) {
        float* tb = Xlds + (kb & 1) * 4096;
        asm volatile("s_waitcnt vmcnt(20)" ::: "memory");   // A(kb) landed
        {
            const float* rbase = tb + (w * 16 + li) * 64;
#pragma unroll
            for (int kc = 0; kc < 2; ++kc) {
                int s0 = (kc * 8 + g * 2)     ^ (li & 7);
                int s1 = (kc * 8 + g * 2 + 1) ^ (li & 7);
                a[kc * 2]     = *reinterpret_cast<const float4*>(rbase + s0 * 4);
                a[kc * 2 + 1] = *reinterpret_cast<const float4*>(rbase + s1 * 4);
            }
        }
        asm volatile("s_waitcnt lgkmcnt(0)" ::: "memory");  // reads retired
        __builtin_amdgcn_sched_barrier(0);
        if (kb + 2 < 12) {
            STAGE64(tb, kb + 2);
            asm volatile("s_waitcnt vmcnt(4)" ::: "memory"); // B(kb) landed
        } else {
            asm volatile("s_waitcnt vmcnt(0)" ::: "memory"); // tail drain
        }
        __builtin_amdgcn_sched_barrier(0);
#pragma unroll
        for (int kc = 0; kc < 2; ++kc) {
            float4 a0 = a[kc * 2], a1 = a[kc * 2 + 1];
            bf8v af;
            af[0] = f2bf(a0.x); af[1] = f2bf(a0.y);
            af[2] = f2bf(a0.z); af[3] = f2bf(a0.w);
            af[4] = f2bf(a1.x); af[5] = f2bf(a1.y);
            af[6] = f2bf(a1.z); af[7] = f2bf(a1.w);
#pragma unroll
            for (int cb = 0; cb < 8; ++cb)
                acc[cb] = __builtin_amdgcn_mfma_f32_16x16x32_bf16(
                              af, breg[kc * 8 + cb], acc[cb], 0, 0, 0);
        }
        if (kb + 1 < 12) ISSUE_B(breg, kb + 1);
    }
#undef STAGE64
#undef ISSUE_B

    // epilogue: bias, norms, pack
    float bpv[8];
#pragma unroll
    for (int cb = 0; cb < 8; ++cb) bpv[cb] = bp[cb * 16 + li];
#pragma unroll
    for (int cb = 0; cb < 8; ++cb)
#pragma unroll
        for (int r = 0; r < 4; ++r) acc[cb][r] += bpv[cb];

#pragma unroll
    for (int r = 0; r < 4; ++r) {
        float s = 0.f;
#pragma unroll
        for (int cb = 0; cb < 8; ++cb) {
            float v = acc[cb][r];
            s += v * v;
        }
        s += __shfl_xor(s, 1);
        s += __shfl_xor(s, 2);
        s += __shfl_xor(s, 4);
        s += __shfl_xor(s, 8);
        int grow = rowblk + w * 16 + 4 * g + r;
        if (li == 0) normv[grow] = (grow < Mreal) ? s : 1e30f;
    }

#pragma unroll
    for (int cb = 0; cb < 8; ++cb) {
        int d = cb * 16 + li;
        int q = d >> 5, g2 = (d & 31) >> 3, j = d & 7;
#pragma unroll
        for (int r = 0; r < 4; ++r) {
            int grow = rowblk + w * 16 + 4 * g + r;
            float v = (grow < Mreal) ? acc[cb][r] : 0.f;
            size_t e = ((size_t)((grow >> 4) * 4 + q) * 64 +
                        (g2 * 16 + (grow & 15))) * 8 + j;
            outP[e] = f2bf(v);
        }
    }
}

// ---------------------------------------------------------------------------
// Kernel 1: k_front — blocks [0,NBX): projX; [NBX,NBX+NBQ): projx;
// rest: labels, 4 rows per wave (stable descending rank of SorP_t[i,Y[i]]).
// ---------------------------------------------------------------------------
__global__ __launch_bounds__(256, 3) void k_front(const float* __restrict__ X,
                                                  const float* __restrict__ x,
                                                  const short* __restrict__ WpP,
                                                  const float* __restrict__ bp,
                                                  short* __restrict__ pXp,
                                                  short* __restrict__ pxq,
                                                  float* __restrict__ kn,
                                                  float* __restrict__ qn,
                                                  const float* __restrict__ S,
                                                  const int* __restrict__ Y,
                                                  int* __restrict__ lab) {
    __shared__ __align__(16) float Xlds[2 * 64 * 64];   // 32 KB
    int b = blockIdx.x;
    if (b < NBX) {
        proj_body(X, WpP, bp, pXp, kn, NTRAIN, b, Xlds);
        return;
    }
    if (b < NBX + NBQ) {
        proj_body(x, WpP, bp, pxq, qn, BQ, b - NBX, Xlds);
        return;
    }
    int w = threadIdx.x >> 6, l = threadIdx.x & 63;
#pragma unroll 1
    for (int r4 = 0; r4 < 4; ++r4) {
        int i = (b - NBX - NBQ) * 16 + w * 4 + r4;
        if (i >= NPAD) continue;
        int cnt = 0;
        if (i < NTRAIN) {
            int y = Y[i];
            float t = S[(size_t)i * NCLS + y];
            float v1 = S[(size_t)i * NCLS + l];
            bool p1 = (v1 > t) || (v1 == t && l < y);
            unsigned long long b1 = __ballot(p1);
            bool p2 = false;
            if (l < NCLS - 64) {
                float v2 = S[(size_t)i * NCLS + 64 + l];
                p2 = (v2 > t) || (v2 == t && (64 + l) < y);
            }
            unsigned long long b2 = __ballot(p2);
            cnt = __popcll(b1) + __popcll(b2);
        }
        if (l == 0) lab[i] = cnt;
    }
}

// ---------------------------------------------------------------------------
// Kernel 4: main fused kernel. Grid (NCH, 8): 128 q-rows/block, dynamic
// tile-stealing per bt (u32 bins -> partition-independent integer totals).
// Per tile: kn/lab prefetch, pXp B-frag ring depth 4, 8 MFMA, exp, drop-self,
// ds_add_u32 bins (stride 102); epilogue stores raw u32 bins to partials.
// ---------------------------------------------------------------------------
__global__ __launch_bounds__(256) void k_main(const short* __restrict__ pxp,
                                              const short* __restrict__ pXp,
                                              const float* __restrict__ qn,
                                              const float* __restrict__ kn,
                                              const int* __restrict__ lab,
                                              unsigned* __restrict__ part,
                                              unsigned* __restrict__ cnt,
                                              int NCH) {
    __shared__ __align__(16) unsigned plds[128 * PSTRIDE];   // 52224 B
    __shared__ int tsh[2];
    const int tid = threadIdx.x;
    const int w = tid >> 6, l = tid & 63, g = l >> 4, li = l & 15;
    const int ch = blockIdx.x;
    const int bt = blockIdx.y;       // 0..7

    for (int s = tid; s < 128 * PSTRIDE; s += 256) plds[s] = 0u;
    if (tid == 0) tsh[0] = (int)atomicAdd(&cnt[bt], 1u);   // first grab
    __syncthreads();

    bf8v af[2][4];                   // px A-frags, persistent
#pragma unroll
    for (int rb = 0; rb < 2; ++rb)
#pragma unroll
        for (int q = 0; q < 4; ++q) {
            int RB = bt * 8 + w * 2 + rb;
            af[rb][q] = *reinterpret_cast<const bf8v*>(
                            pxp + (size_t)((RB * 4 + q) * 64 + l) * 8);
        }
    float qnv[2][4];
#pragma unroll
    for (int rb = 0; rb < 2; ++rb)
#pragma unroll
        for (int r = 0; r < 4; ++r)
            qnv[rb][r] = qn[bt * 128 + w * 32 + rb * 16 + 4 * g + r];

    int t = tsh[0];
    int pp = 1;
#pragma unroll 1
    while (t < NTILES) {
        if (tid == 0) tsh[pp] = (int)atomicAdd(&cnt[bt], 1u);   // prefetch next
        const int i0 = t * 128;
        const int RB0 = i0 >> 4;
        float knv8[8];
        int   labv8[8];
#pragma unroll
        for (int ib = 0; ib < 8; ++ib) {
            knv8[ib]  = kn[i0 + ib * 16 + li];
            labv8[ib] = lab[i0 + ib * 16 + li];
        }
        // B-frag ring: 3 sub-tiles in flight
        bf8v bfr[4][4];
#pragma unroll
        for (int p = 0; p < 3; ++p)
#pragma unroll
            for (int q = 0; q < 4; ++q)
                bfr[p][q] = *reinterpret_cast<const bf8v*>(
                    pXp + (size_t)(((RB0 + p) * 4 + q) * 64 + l) * 8);
#pragma unroll
        for (int ib = 0; ib < 8; ++ib) {
            if (ib + 3 < 8) {
#pragma unroll
                for (int q = 0; q < 4; ++q)
                    bfr[(ib + 3) & 3][q] = *reinterpret_cast<const bf8v*>(
                        pXp + (size_t)(((RB0 + ib + 3) * 4 + q) * 64 + l) * 8);
            }
            f32x4 s0 = (f32x4){0.f, 0.f, 0.f, 0.f};
            f32x4 s1 = (f32x4){0.f, 0.f, 0.f, 0.f};
#pragma unroll
            for (int q = 0; q < 4; ++q) {
                s0 = __builtin_amdgcn_mfma_f32_16x16x32_bf16(af[0][q], bfr[ib & 3][q], s0, 0, 0, 0);
                s1 = __builtin_amdgcn_mfma_f32_16x16x32_bf16(af[1][q], bfr[ib & 3][q], s1, 0, 0, 0);
            }
            const float knv  = knv8[ib];
            const int   labv = labv8[ib];
#pragma unroll
            for (int rb = 0; rb < 2; ++rb) {
                f32x4 sv = rb ? s1 : s0;
#pragma unroll
                for (int r = 0; r < 4; ++r) {
                    float sqd = qnv[rb][r] + knv - 2.f * sv[r];
                    float kis = __expf(sqd * (-1.f / 256.f));
                    kis = (kis < 1.0f) ? kis : 0.f;   // drop_self (1-1e-10 == 1.0f)
                    unsigned qv = (unsigned)__float2uint_rn(kis * FIXS);
                    int rowl = w * 32 + rb * 16 + 4 * g + r;
                    atomicAdd(&plds[rowl * PSTRIDE + labv], qv);   // ds_add_u32
                }
            }
        }
        __syncthreads();             // next grab visible; tsh slot reusable
        t = tsh[pp];
        pp ^= 1;
    }

    // epilogue: flush raw u32 bins (rows owned by this wave; no barrier needed)
#pragma unroll 1
    for (int rr = 0; rr < 32; ++rr) {
        int row = w * 32 + rr;
        if (l < PSTRIDE / 2) {   // 51 lanes -> cols 0..101
            uint2 u = *reinterpret_cast<const uint2*>(&plds[row * PSTRIDE + l * 2]);
            int grow = bt * 128 + row;
            *reinterpret_cast<uint2*>(
                &part[((size_t)grow * NCH + ch) * PCOLS + l * 2]) = u;
        }
    }
}

// ---------------------------------------------------------------------------
// Kernel 5: fused reduce + normalize + rank-gather. 256 threads, 2-way split
// u32 reduction (exact, partition-independent), float only at the end.
// ---------------------------------------------------------------------------
__global__ __launch_bounds__(256) void k_final(const unsigned* __restrict__ part,
                                               const float* __restrict__ SorPq,
                                               float* __restrict__ out,
                                               int NCH) {
    __shared__ float sp[NCLS];
    __shared__ unsigned pr2[2][PCOLS];
    int t = threadIdx.x, b = blockIdx.x;
    int c = t & 127, h = t >> 7;
    if (h == 1 && c < NCLS) sp[c] = SorPq[(size_t)b * NCLS + c];
    if (c < NCLS) {
        unsigned s = 0u;
        int half = NCH >> 1;
        const unsigned* p = part + ((size_t)b * NCH + (size_t)h * half) * PCOLS + c;
        for (int ch = 0; ch < half; ++ch) s += p[(size_t)ch * PCOLS];
        pr2[h][c] = s;
    }
    __syncthreads();
    if (t < NCLS) pr2[0][t] += pr2[1][t];   // exact u32 total (< 2^32)
    __syncthreads();
    if (t < NCLS) {
        float tot = 0.f;
        for (int k = 0; k < NCLS; ++k)
            tot += (float)pr2[0][k] * FIXI;   // fixed order, deterministic
        float s = sp[t];
        int r = 0;
        for (int k = 0; k < NCLS; ++k) {
            float sk = sp[k];
            r += (sk > s || (sk == s && k < t)) ? 1 : 0;
        }
        out[(size_t)b * NCLS + t] = ((float)pr2[0][r] * FIXI) / tot;
    }
}

// ---------------------------------------------------------------------------
extern "C" void kernel_launch(void* const* d_in, const int* in_sizes, int n_in,
                              void* d_out, int out_size, void* d_ws, size_t ws_size,
                              hipStream_t stream) {
    const float* x    = (const float*)d_in[0];   // [1024,768]
    const float* X    = (const float*)d_in[1];   // [50000,768]
    const float* Wp   = (const float*)d_in[2];   // [768,128]
    const float* bp   = (const float*)d_in[3];   // [128]
    const int*   Y    = (const int*)  d_in[4];   // [50000]
    const float* SPt  = (const float*)d_in[5];   // [50000,100]
    const float* SPq  = (const float*)d_in[6];   // [1024,100]
    float* out = (float*)d_out;                  // [1024,100]

    char* ws = (char*)d_ws;
    short* WpP = (short*)(ws + 0);                       //   196,608
    short* pXp = (short*)(ws + 196608);                  // 12,812,288
    short* pxq = (short*)(ws + 13008896);                //    262,144
    float* kn  = (float*)(ws + 13271040);                //    200,192
    float* qn  = (float*)(ws + 13471232);                //      4,096
    int*   lab = (int*)  (ws + 13475328);                //    200,192
    unsigned* cnt  = (unsigned*)(ws + 13675520);         //        128 (8 used)
    unsigned* part = (unsigned*)(ws + 13675648);         // NCH*1024*104*4

    const size_t base = 13675648;
    const size_t per  = (size_t)BQ * PCOLS * 4;   // bytes per chunk slice (u32)
    int NCH = 96;
    if (ws_size > base) {
        size_t fit = (ws_size - base) / per;
        if ((size_t)NCH > fit) NCH = (int)fit;
    } else {
        NCH = 8;
    }
    NCH &= ~7;
    if (NCH < 8) NCH = 8;

    k_pack_wp<<<48, 256, 0, stream>>>(Wp, WpP, cnt);
    k_front<<<NBX + NBQ + NBL, 256, 0, stream>>>(X, x, WpP, bp, pXp, pxq,
                                                 kn, qn, SPt, Y, lab);
    k_main<<<dim3(NCH, 8), 256, 0, stream>>>(pxq, pXp, qn, kn, lab, part, cnt, NCH);
    k_final<<<BQ, 256, 0, stream>>>(part, SPq, out, NCH);
}

// Round 20
// 110.136 us; speedup vs baseline: 1.1713x; 1.1713x over previous
//
#include <hip/hip_runtime.h>

// ---------------------------------------------------------------------------
// KernelClassifier: px = x@Wp+bp; pX = X@Wp+bp; Kis = exp(-||px-pX||^2/256)
// (drop self: Kis<1.0f), pred[b,lab[i]] += Kis[b,i], normalize, rank-gather.
// R4: LDS fp32 atomicAdd = CAS loop -> fixed-point ds_add_u32 (451->216us).
// R11-R13: counted-vmcnt pipelines, bank fix, kernel merges (216->112us).
// R14-R17: staging/redundancy/concurrency levers all null/negative.
// R19: dynamic tile-stealing REGRESSED (+18us: cross-XCD counter atomics +
//     per-tile barriers + u32 part traffic). Reverted.
// R20 (final): byte-exact R18 — the measured optimum, 110.58us.
// ---------------------------------------------------------------------------

typedef short  bf8v  __attribute__((ext_vector_type(8)));   // 8 x bf16 (4 VGPR)
typedef float  f32x4 __attribute__((ext_vector_type(4)));   // MFMA C/D

#define NTRAIN 50000
#define NPAD   50048          // 391 * 128
#define NTILES 391
#define BQ     1024
#define DIN    768
#define DP     128
#define NCLS   100
#define PSTRIDE 102           // LDS bins stride: 102%32=6 -> g-lanes spread
#define PCOLS  104            // partial row width (u32-pair aligned)
#define FIXS   2097152.0f     // 2^21 fixed-point scale
#define FIXI   (1.0f / 2097152.0f)
#define NBX    (NPAD / 64)    // 782 projX blocks
#define NBQ    (BQ / 64)      // 16 projx blocks
#define NBL    ((NPAD + 15) / 16)   // label blocks: 4 waves x 4 rows each

__device__ __forceinline__ short f2bf(float x) {   // fp32 -> bf16 RNE
    unsigned u = __float_as_uint(x);
    u += 0x7FFFu + ((u >> 16) & 1u);
    return (short)(u >> 16);
}
__device__ __forceinline__ float bf2f(unsigned short u) {
    return __uint_as_float((unsigned)u << 16);
}

#define AS1U(p) ((const __attribute__((address_space(1))) unsigned int*)(unsigned long long)(p))
#define AS3U(p) ((__attribute__((address_space(3))) unsigned int*)(unsigned int)(unsigned long long)(p))

// ---------------------------------------------------------------------------
// Kernel 0: pack Wp into B-fragment order (precedes k_front's proj)
// ---------------------------------------------------------------------------
__global__ __launch_bounds__(256) void k_pack_wp(const float* __restrict__ Wp,
                                                 short* __restrict__ WpP) {
    int tid = blockIdx.x * 256 + threadIdx.x;
    if (tid >= 24 * 8 * 64) return;
    int l = tid & 63, cb = (tid >> 6) & 7, q = tid >> 9;
    int c = cb * 16 + (l & 15);
    int g = l >> 4;
    bf8v o;
#pragma unroll
    for (int j = 0; j < 8; ++j) {
        int k = q * 32 + g * 8 + j;
        o[j] = f2bf(Wp[k * DP + c]);
    }
    *reinterpret_cast<bf8v*>(WpP + (size_t)tid * 8) = o;
}

// ---------------------------------------------------------------------------
// proj body (R13/R15 pipeline): BM=64, 4 waves x 16 rows, barrier-free,
// counted vmcnt, depth-2 A staging, single-buffer B regs.
// ---------------------------------------------------------------------------
__device__ __forceinline__ void proj_body(const float* __restrict__ Xin,
                                          const short* __restrict__ WpP,
                                          const float* __restrict__ bp,
                                          short* __restrict__ outP,
                                          float* __restrict__ normv,
                                          int Mreal, int blk,
                                          float* __restrict__ Xlds) {
    const int tid = threadIdx.x;
    const int w = tid >> 6, l = tid & 63, g = l >> 4, li = l & 15;
    const int rowblk = blk * 64;

    f32x4 acc[8];
#pragma unroll
    for (int cb = 0; cb < 8; ++cb) acc[cb] = (f32x4){0.f, 0.f, 0.f, 0.f};

#define STAGE64(lbuf, kb)                                                     \
    {                                                                         \
        _Pragma("unroll")                                                     \
        for (int it = 0; it < 4; ++it) {                                      \
            int s  = w * 256 + it * 64 + l;                                   \
            int r  = s >> 4;                                                  \
            int c4 = (s & 15) ^ (r & 7);                                      \
            int rg = rowblk + r;                                              \
            rg = (rg < Mreal) ? rg : (Mreal - 1);                             \
            const float* gp = Xin + (size_t)rg * DIN + (kb) * 64 + c4 * 4;    \
            const float* lp = (lbuf) + (w * 256 + it * 64) * 4;               \
            __builtin_amdgcn_global_load_lds(AS1U(gp), AS3U(lp), 16, 0, 0);   \
        }                                                                     \
    }
#define ISSUE_B(dst, kb)                                                      \
    {                                                                         \
        _Pragma("unroll")                                                     \
        for (int f = 0; f < 16; ++f)                                          \
            dst[f] = *reinterpret_cast<const bf8v*>(                          \
                WpP + ((size_t)((kb) * 16 + f) * 64 + l) * 8);                \
    }

    bf8v breg[16];
    float4 a[4];

    STAGE64(Xlds, 0);
    STAGE64(Xlds + 4096, 1);
    ISSUE_B(breg, 0);

#pragma unroll 1
    for (int kb = 0; kb < 12; ++kb) {
        float* tb = Xlds + (kb & 1) * 4096;
        asm volatile("s_waitcnt vmcnt(20)" ::: "memory");   // A(kb) landed
        {
            const float* rbase = tb + (w * 16 + li) * 64;
#pragma unroll
            for (int kc = 0; kc < 2; ++kc) {
                int s0 = (kc * 8 + g * 2)     ^ (li & 7);
                int s1 = (kc * 8 + g * 2 + 1) ^ (li & 7);
                a[kc * 2]     = *reinterpret_cast<const float4*>(rbase + s0 * 4);
                a[kc * 2 + 1] = *reinterpret_cast<const float4*>(rbase + s1 * 4);
            }
        }
        asm volatile("s_waitcnt lgkmcnt(0)" ::: "memory");  // reads retired
        __builtin_amdgcn_sched_barrier(0);
        if (kb + 2 < 12) {
            STAGE64(tb, kb + 2);
            asm volatile("s_waitcnt vmcnt(4)" ::: "memory"); // B(kb) landed
        } else {
            asm volatile("s_waitcnt vmcnt(0)" ::: "memory"); // tail drain
        }
        __builtin_amdgcn_sched_barrier(0);
#pragma unroll
        for (int kc = 0; kc < 2; ++kc) {
            float4 a0 = a[kc * 2], a1 = a[kc * 2 + 1];
            bf8v af;
            af[0] = f2bf(a0.x); af[1] = f2bf(a0.y);
            af[2] = f2bf(a0.z); af[3] = f2bf(a0.w);
            af[4] = f2bf(a1.x); af[5] = f2bf(a1.y);
            af[6] = f2bf(a1.z); af[7] = f2bf(a1.w);
#pragma unroll
            for (int cb = 0; cb < 8; ++cb)
                acc[cb] = __builtin_amdgcn_mfma_f32_16x16x32_bf16(
                              af, breg[kc * 8 + cb], acc[cb], 0, 0, 0);
        }
        if (kb + 1 < 12) ISSUE_B(breg, kb + 1);
    }
#undef STAGE64
#undef ISSUE_B

    // epilogue: bias, norms, pack
    float bpv[8];
#pragma unroll
    for (int cb = 0; cb < 8; ++cb) bpv[cb] = bp[cb * 16 + li];
#pragma unroll
    for (int cb = 0; cb < 8; ++cb)
#pragma unroll
        for (int r = 0; r < 4; ++r) acc[cb][r] += bpv[cb];

#pragma unroll
    for (int r = 0; r < 4; ++r) {
        float s = 0.f;
#pragma unroll
        for (int cb = 0; cb < 8; ++cb) {
            float v = acc[cb][r];
            s += v * v;
        }
        s += __shfl_xor(s, 1);
        s += __shfl_xor(s, 2);
        s += __shfl_xor(s, 4);
        s += __shfl_xor(s, 8);
        int grow = rowblk + w * 16 + 4 * g + r;
        if (li == 0) normv[grow] = (grow < Mreal) ? s : 1e30f;
    }

#pragma unroll
    for (int cb = 0; cb < 8; ++cb) {
        int d = cb * 16 + li;
        int q = d >> 5, g2 = (d & 31) >> 3, j = d & 7;
#pragma unroll
        for (int r = 0; r < 4; ++r) {
            int grow = rowblk + w * 16 + 4 * g + r;
            float v = (grow < Mreal) ? acc[cb][r] : 0.f;
            size_t e = ((size_t)((grow >> 4) * 4 + q) * 64 +
                        (g2 * 16 + (grow & 15))) * 8 + j;
            outP[e] = f2bf(v);
        }
    }
}

// ---------------------------------------------------------------------------
// Kernel 1: k_front — blocks [0,NBX): projX; [NBX,NBX+NBQ): projx;
// rest: labels, 4 rows per wave (stable descending rank of SorP_t[i,Y[i]]).
// ---------------------------------------------------------------------------
__global__ __launch_bounds__(256, 3) void k_front(const float* __restrict__ X,
                                                  const float* __restrict__ x,
                                                  const short* __restrict__ WpP,
                                                  const float* __restrict__ bp,
                                                  short* __restrict__ pXp,
                                                  short* __restrict__ pxq,
                                                  float* __restrict__ kn,
                                                  float* __restrict__ qn,
                                                  const float* __restrict__ S,
                                                  const int* __restrict__ Y,
                                                  int* __restrict__ lab) {
    __shared__ __align__(16) float Xlds[2 * 64 * 64];   // 32 KB
    int b = blockIdx.x;
    if (b < NBX) {
        proj_body(X, WpP, bp, pXp, kn, NTRAIN, b, Xlds);
        return;
    }
    if (b < NBX + NBQ) {
        proj_body(x, WpP, bp, pxq, qn, BQ, b - NBX, Xlds);
        return;
    }
    int w = threadIdx.x >> 6, l = threadIdx.x & 63;
#pragma unroll 1
    for (int r4 = 0; r4 < 4; ++r4) {
        int i = (b - NBX - NBQ) * 16 + w * 4 + r4;
        if (i >= NPAD) continue;
        int cnt = 0;
        if (i < NTRAIN) {
            int y = Y[i];
            float t = S[(size_t)i * NCLS + y];
            float v1 = S[(size_t)i * NCLS + l];
            bool p1 = (v1 > t) || (v1 == t && l < y);
            unsigned long long b1 = __ballot(p1);
            bool p2 = false;
            if (l < NCLS - 64) {
                float v2 = S[(size_t)i * NCLS + 64 + l];
                p2 = (v2 > t) || (v2 == t && (64 + l) < y);
            }
            unsigned long long b2 = __ballot(p2);
            cnt = __popcll(b1) + __popcll(b2);
        }
        if (l == 0) lab[i] = cnt;
    }
}

// ---------------------------------------------------------------------------
// Kernel 4: main fused kernel (R15 form). Grid (NCH, 8): 128 q-rows/block.
// Per i-tile: kn/lab prefetch, pXp B-frag ring depth 4 (3 ahead), 8 MFMA,
// Kis = exp(-(qn+kn-2dot)/256), drop-self, ds_add_u32 bins (stride 102),
// bf16 stores to per-chunk partials.
// ---------------------------------------------------------------------------
__global__ __launch_bounds__(256) void k_main(const short* __restrict__ pxp,
                                              const short* __restrict__ pXp,
                                              const float* __restrict__ qn,
                                              const float* __restrict__ kn,
                                              const int* __restrict__ lab,
                                              unsigned short* __restrict__ part,
                                              int NCH) {
    __shared__ __align__(16) unsigned plds[128 * PSTRIDE];   // 52224 B
    const int tid = threadIdx.x;
    const int w = tid >> 6, l = tid & 63, g = l >> 4, li = l & 15;
    const int ch = blockIdx.x;
    const int bt = blockIdx.y;       // 0..7

    for (int s = tid; s < 128 * PSTRIDE; s += 256) plds[s] = 0u;
    __syncthreads();                 // only barrier in the kernel

    bf8v af[2][4];                   // px A-frags, persistent
#pragma unroll
    for (int rb = 0; rb < 2; ++rb)
#pragma unroll
        for (int q = 0; q < 4; ++q) {
            int RB = bt * 8 + w * 2 + rb;
            af[rb][q] = *reinterpret_cast<const bf8v*>(
                            pxp + (size_t)((RB * 4 + q) * 64 + l) * 8);
        }
    float qnv[2][4];
#pragma unroll
    for (int rb = 0; rb < 2; ++rb)
#pragma unroll
        for (int r = 0; r < 4; ++r)
            qnv[rb][r] = qn[bt * 128 + w * 32 + rb * 16 + 4 * g + r];

#pragma unroll 1
    for (int t = ch; t < NTILES; t += NCH) {
        const int i0 = t * 128;
        const int RB0 = i0 >> 4;
        float knv8[8];
        int   labv8[8];
#pragma unroll
        for (int ib = 0; ib < 8; ++ib) {
            knv8[ib]  = kn[i0 + ib * 16 + li];
            labv8[ib] = lab[i0 + ib * 16 + li];
        }
        // B-frag ring: 3 sub-tiles in flight
        bf8v bfr[4][4];
#pragma unroll
        for (int p = 0; p < 3; ++p)
#pragma unroll
            for (int q = 0; q < 4; ++q)
                bfr[p][q] = *reinterpret_cast<const bf8v*>(
                    pXp + (size_t)(((RB0 + p) * 4 + q) * 64 + l) * 8);
#pragma unroll
        for (int ib = 0; ib < 8; ++ib) {
            if (ib + 3 < 8) {
#pragma unroll
                for (int q = 0; q < 4; ++q)
                    bfr[(ib + 3) & 3][q] = *reinterpret_cast<const bf8v*>(
                        pXp + (size_t)(((RB0 + ib + 3) * 4 + q) * 64 + l) * 8);
            }
            f32x4 s0 = (f32x4){0.f, 0.f, 0.f, 0.f};
            f32x4 s1 = (f32x4){0.f, 0.f, 0.f, 0.f};
#pragma unroll
            for (int q = 0; q < 4; ++q) {
                s0 = __builtin_amdgcn_mfma_f32_16x16x32_bf16(af[0][q], bfr[ib & 3][q], s0, 0, 0, 0);
                s1 = __builtin_amdgcn_mfma_f32_16x16x32_bf16(af[1][q], bfr[ib & 3][q], s1, 0, 0, 0);
            }
            const float knv  = knv8[ib];
            const int   labv = labv8[ib];
#pragma unroll
            for (int rb = 0; rb < 2; ++rb) {
                f32x4 sv = rb ? s1 : s0;
#pragma unroll
                for (int r = 0; r < 4; ++r) {
                    float sqd = qnv[rb][r] + knv - 2.f * sv[r];
                    float kis = __expf(sqd * (-1.f / 256.f));
                    kis = (kis < 1.0f) ? kis : 0.f;   // drop_self (1-1e-10 == 1.0f)
                    unsigned qv = (unsigned)__float2uint_rn(kis * FIXS);
                    int rowl = w * 32 + rb * 16 + 4 * g + r;
                    atomicAdd(&plds[rowl * PSTRIDE + labv], qv);   // ds_add_u32
                }
            }
        }
    }

    // epilogue: flush bins as packed bf16 pairs (4B stores, aligned)
#pragma unroll 1
    for (int rr = 0; rr < 32; ++rr) {
        int row = w * 32 + rr;
        if (l < PSTRIDE / 2) {   // 51 lanes -> cols 0..101
            uint2 u = *reinterpret_cast<const uint2*>(&plds[row * PSTRIDE + l * 2]);
            float vx = (float)u.x * FIXI, vy = (float)u.y * FIXI;
            unsigned pk = (unsigned)(unsigned short)f2bf(vx) |
                          ((unsigned)(unsigned short)f2bf(vy) << 16);
            int grow = bt * 128 + row;
            *reinterpret_cast<unsigned*>(
                &part[((size_t)grow * NCH + ch) * PCOLS + l * 2]) = pk;
        }
    }
}

// ---------------------------------------------------------------------------
// Kernel 5: fused reduce + normalize + rank-gather. 256 threads, 2-way split
// reduction over bf16 partials.
// ---------------------------------------------------------------------------
__global__ __launch_bounds__(256) void k_final(const unsigned short* __restrict__ part,
                                               const float* __restrict__ SorPq,
                                               float* __restrict__ out,
                                               int NCH) {
    __shared__ float sp[NCLS];
    __shared__ float pr2[2][PCOLS];
    int t = threadIdx.x, b = blockIdx.x;
    int c = t & 127, h = t >> 7;
    if (h == 1 && c < NCLS) sp[c] = SorPq[(size_t)b * NCLS + c];
    if (c < NCLS) {
        float s = 0.f;
        int half = NCH >> 1;
        const unsigned short* p =
            part + ((size_t)b * NCH + (size_t)h * half) * PCOLS + c;
        for (int ch = 0; ch < half; ++ch) s += bf2f(p[(size_t)ch * PCOLS]);
        pr2[h][c] = s;
    }
    __syncthreads();
    if (t < NCLS) pr2[0][t] += pr2[1][t];
    __syncthreads();
    if (t < NCLS) {
        float tot = 0.f;
        for (int k = 0; k < NCLS; ++k) tot += pr2[0][k];  // broadcast, deterministic
        float s = sp[t];
        int r = 0;
        for (int k = 0; k < NCLS; ++k) {
            float sk = sp[k];
            r += (sk > s || (sk == s && k < t)) ? 1 : 0;
        }
        out[(size_t)b * NCLS + t] = pr2[0][r] / tot;
    }
}

// ---------------------------------------------------------------------------
extern "C" void kernel_launch(void* const* d_in, const int* in_sizes, int n_in,
                              void* d_out, int out_size, void* d_ws, size_t ws_size,
                              hipStream_t stream) {
    const float* x    = (const float*)d_in[0];   // [1024,768]
    const float* X    = (const float*)d_in[1];   // [50000,768]
    const float* Wp   = (const float*)d_in[2];   // [768,128]
    const float* bp   = (const float*)d_in[3];   // [128]
    const int*   Y    = (const int*)  d_in[4];   // [50000]
    const float* SPt  = (const float*)d_in[5];   // [50000,100]
    const float* SPq  = (const float*)d_in[6];   // [1024,100]
    float* out = (float*)d_out;                  // [1024,100]

    char* ws = (char*)d_ws;
    short* WpP = (short*)(ws + 0);                       //   196,608
    short* pXp = (short*)(ws + 196608);                  // 12,812,288
    short* pxq = (short*)(ws + 13008896);                //    262,144
    float* kn  = (float*)(ws + 13271040);                //    200,192
    float* qn  = (float*)(ws + 13471232);                //      4,096
    int*   lab = (int*)  (ws + 13475328);                //    200,192
    unsigned short* part = (unsigned short*)(ws + 13675520);  // NCH*1024*104*2

    const size_t base = 13675520;
    const size_t per  = (size_t)BQ * PCOLS * 2;   // bytes per chunk slice (bf16)
    int NCH = 96;
    if (ws_size > base) {
        size_t fit = (ws_size - base) / per;
        if ((size_t)NCH > fit) NCH = (int)fit;
    } else {
        NCH = 8;
    }
    NCH &= ~7;
    if (NCH < 8) NCH = 8;

    k_pack_wp<<<48, 256, 0, stream>>>(Wp, WpP);
    k_front<<<NBX + NBQ + NBL, 256, 0, stream>>>(X, x, WpP, bp, pXp, pxq,
                                                 kn, qn, SPt, Y, lab);
    k_main<<<dim3(NCH, 8), 256, 0, stream>>>(pxq, pXp, qn, kn, lab, part, NCH);
    k_final<<<BQ, 256, 0, stream>>>(part, SPq, out, NCH);
}